// Round 1
// baseline (5934.378 us; speedup 1.0000x reference)
//
#include <hip/hip_runtime.h>

#define CDIV(a,b) (((a)+(b)-1)/(b))

// ---------------- utility kernels ----------------

__global__ void zero_f4(float4* __restrict__ p, long long n4) {
    long long i = blockIdx.x * 256LL + threadIdx.x;
    if (i < n4) p[i] = make_float4(0.f, 0.f, 0.f, 0.f);
}

// out[k*ncat + col0 + n] = coeff[2r]*basis[k*N+n] + coeff[2r+1]*basis[KN + k*N+n]
__global__ void fill_basis_block(float* __restrict__ out, int ncat, int col0,
                                 const float* __restrict__ basis, long long KN,
                                 const float* __restrict__ coeff, int r, int N,
                                 long long total) {
    long long i = blockIdx.x * 256LL + threadIdx.x;
    if (i >= total) return;
    int k = (int)(i / N), n = (int)(i % N);
    float c0 = coeff[2 * r], c1 = coeff[2 * r + 1];
    out[(long long)k * ncat + col0 + n] = c0 * basis[i] + c1 * basis[KN + i];
}

__global__ void fill_copy_block(float* __restrict__ out, int ncat, int col0,
                                const float* __restrict__ src, int N, long long total) {
    long long i = blockIdx.x * 256LL + threadIdx.x;
    if (i >= total) return;
    int k = (int)(i / N), n = (int)(i % N);
    out[(long long)k * ncat + col0 + n] = src[i];
}

__global__ void accum_deg(const int* __restrict__ dst, int n, float* __restrict__ deg) {
    int i = blockIdx.x * 256 + threadIdx.x;
    if (i < n) atomicAdd(&deg[dst[i]], 1.0f);
}

__global__ void invert_deg(float* __restrict__ deg, int n) {
    int i = blockIdx.x * 256 + threadIdx.x;
    if (i < n) deg[i] = 1.0f / fmaxf(deg[i], 1.0f);
}

// ---------------- GEMM: C[M,N] = A[M,K] @ B[K,N], fp32, 64x64 tile ----------------
// requires: K % 16 == 0, N % 64 == 0; M arbitrary.
__global__ __launch_bounds__(256) void gemm_f32(
    const float* __restrict__ A, const float* __restrict__ B, float* __restrict__ C,
    int M, int K, int N) {
    __shared__ float As[16][64];   // As[k][m]
    __shared__ float Bs[16][64];   // Bs[k][n]
    const int bm = blockIdx.x * 64;
    const int bn = blockIdx.y * 64;
    const int tid = threadIdx.x;
    const int tx = tid & 15;   // n dir
    const int ty = tid >> 4;   // m dir
    float acc[4][4] = {{0.f}};
    for (int k0 = 0; k0 < K; k0 += 16) {
        // A tile: 64 rows x 16 k, each thread loads float4 along k, stores transposed
        {
            int ar = tid >> 2;            // 0..63
            int ak = (tid & 3) << 2;      // 0,4,8,12
            float4 a4 = make_float4(0.f, 0.f, 0.f, 0.f);
            if (bm + ar < M) a4 = *(const float4*)&A[(size_t)(bm + ar) * K + k0 + ak];
            As[ak + 0][ar] = a4.x; As[ak + 1][ar] = a4.y;
            As[ak + 2][ar] = a4.z; As[ak + 3][ar] = a4.w;
        }
        // B tile: 16 k x 64 n
        {
            int bk = tid >> 4;            // 0..15
            int bnn = (tid & 15) << 2;    // 0..60
            *(float4*)&Bs[bk][bnn] = *(const float4*)&B[(size_t)(k0 + bk) * N + bn + bnn];
        }
        __syncthreads();
#pragma unroll
        for (int k = 0; k < 16; ++k) {
            float4 av = *(float4*)&As[k][ty << 2];
            float4 bv = *(float4*)&Bs[k][tx << 2];
            acc[0][0] += av.x * bv.x; acc[0][1] += av.x * bv.y; acc[0][2] += av.x * bv.z; acc[0][3] += av.x * bv.w;
            acc[1][0] += av.y * bv.x; acc[1][1] += av.y * bv.y; acc[1][2] += av.y * bv.z; acc[1][3] += av.y * bv.w;
            acc[2][0] += av.z * bv.x; acc[2][1] += av.z * bv.y; acc[2][2] += av.z * bv.z; acc[2][3] += av.z * bv.w;
            acc[3][0] += av.w * bv.x; acc[3][1] += av.w * bv.y; acc[3][2] += av.w * bv.z; acc[3][3] += av.w * bv.w;
        }
        __syncthreads();
    }
#pragma unroll
    for (int i = 0; i < 4; ++i) {
        int r = bm + (ty << 2) + i;
        if (r < M)
            *(float4*)&C[(size_t)r * N + bn + (tx << 2)] =
                make_float4(acc[i][0], acc[i][1], acc[i][2], acc[i][3]);
    }
}

// ---------------- scatter-mean: agg[dst] += y[src, yoff:yoff+F] * invdeg[dst] ----------------
// one thread per (edge, float4-chunk); lc = log2(F/4)
__global__ void scatter_mean(const float* __restrict__ y, int ystride, int yoff,
                             const int* __restrict__ src, const int* __restrict__ dst,
                             const float* __restrict__ invdeg, float* __restrict__ agg,
                             int F, int lc, long long nwork) {
    long long i = blockIdx.x * 256LL + threadIdx.x;
    if (i >= nwork) return;
    int e = (int)(i >> lc);
    int c = (int)(i & ((1 << lc) - 1));
    int s = src[e], d = dst[e];
    float4 v = *(const float4*)&y[(size_t)s * ystride + yoff + (c << 2)];
    float wgt = invdeg[d];
    float* p = &agg[(size_t)d * F + (c << 2)];
    atomicAdd(p + 0, v.x * wgt);
    atomicAdd(p + 1, v.y * wgt);
    atomicAdd(p + 2, v.z * wgt);
    atomicAdd(p + 3, v.w * wgt);
}

// ---------------- combine: h = relu(agg + y[:, yoff:yoff+F] + bias), in place ----------------
__global__ void combine_relu(float* __restrict__ agg, const float* __restrict__ y,
                             int ystride, int yoff, const float* __restrict__ bias,
                             int F, int lc, long long n4) {
    long long i = blockIdx.x * 256LL + threadIdx.x;
    if (i >= n4) return;
    int node = (int)(i >> lc);
    int c = (int)(i & ((1 << lc) - 1)) << 2;
    float4 a = *(float4*)&agg[(size_t)node * F + c];
    float4 l = *(const float4*)&y[(size_t)node * ystride + yoff + c];
    float4 r;
    r.x = fmaxf(a.x + l.x + bias[c + 0], 0.f);
    r.y = fmaxf(a.y + l.y + bias[c + 1], 0.f);
    r.z = fmaxf(a.z + l.z + bias[c + 2], 0.f);
    r.w = fmaxf(a.w + l.w + bias[c + 3], 0.f);
    *(float4*)&agg[(size_t)node * F + c] = r;
}

__global__ void init_out(float* __restrict__ out, const float* __restrict__ b, int G) {
    int i = threadIdx.x;
    if (i < G) out[i] = b[0];
}

// one wave per node: s = dot(h[node], w); LDS-bin by gid; flush per block
__global__ void score_reduce(const float* __restrict__ h, const float* __restrict__ w,
                             const int* __restrict__ gid, int F, int n_nodes,
                             float* __restrict__ out, int G) {
    __shared__ float part[64];
    for (int i = threadIdx.x; i < 64; i += blockDim.x) part[i] = 0.f;
    __syncthreads();
    int lane = threadIdx.x & 63;
    int wavesPerBlock = blockDim.x >> 6;
    int wave = blockIdx.x * wavesPerBlock + (threadIdx.x >> 6);
    int nwaves = gridDim.x * wavesPerBlock;
    for (int node = wave; node < n_nodes; node += nwaves) {
        float s = 0.f;
        for (int f = lane; f < F; f += 64) s += h[(size_t)node * F + f] * w[f];
#pragma unroll
        for (int off = 32; off; off >>= 1) s += __shfl_down(s, off);
        if (lane == 0) atomicAdd(&part[gid[node]], s);
    }
    __syncthreads();
    for (int i = threadIdx.x; i < G; i += blockDim.x)
        atomicAdd(&out[i], part[i]);
}

// ---------------- launch ----------------

extern "C" void kernel_launch(void* const* d_in, const int* in_sizes, int n_in,
                              void* d_out, int out_size, void* d_ws, size_t ws_size,
                              hipStream_t stream) {
    const float* x_sent = (const float*)d_in[0];
    const float* x_doc  = (const float*)d_in[1];
    const float* coeff1 = (const float*)d_in[2];
    const float* basis1 = (const float*)d_in[3];
    const float* loopw1 = (const float*)d_in[4];
    const float* bias1  = (const float*)d_in[5];
    const float* coeff2 = (const float*)d_in[6];
    const float* basis2 = (const float*)d_in[7];
    const float* loopw2 = (const float*)d_in[8];
    const float* bias2  = (const float*)d_in[9];
    const float* wscore = (const float*)d_in[10];
    const float* bscore = (const float*)d_in[11];
    const int* src_ss = (const int*)d_in[12];
    const int* dst_ss = (const int*)d_in[13];
    const int* src_sd = (const int*)d_in[14];
    const int* dst_sd = (const int*)d_in[15];
    const int* src_ds = (const int*)d_in[16];
    const int* dst_ds = (const int*)d_in[17];
    const int* gid_sent = (const int*)d_in[18];
    const int* gid_doc  = (const int*)d_in[19];

    const int DIN = 768, DH = 256, DOo = 128;
    const int NS = in_sizes[0] / DIN;     // 100000
    const int ND = in_sizes[1] / DIN;     // 10000
    const int E_SS = in_sizes[12], E_SD = in_sizes[14], E_DS = in_sizes[16];
    const int G = out_size;               // 32
    float* out = (float*)d_out;

    // workspace layout (floats)
    float* ws = (float*)d_ws;
    size_t o = 0;
    float* B1s = ws + o; o += (size_t)DIN * (2 * DH + DH);        // 768 x 768
    float* B1d = ws + o; o += (size_t)DIN * (2 * DH);             // 768 x 512
    float* B2s = ws + o; o += (size_t)DH * (3 * DOo);             // 256 x 384
    float* B2d = ws + o; o += (size_t)DH * (2 * DOo);             // 256 x 256
    float* invdeg_ss = ws + o; o += NS;
    float* invdeg_ds = ws + o; o += NS;
    float* invdeg_sd = ws + o; o += ND;
    float* ys1 = ws + o; o += (size_t)NS * 768;                   // big staging
    float* yd1 = ws + o; o += (size_t)ND * 512;
    float* aggs = ws + o; o += (size_t)NS * DH;                   // layer-1 sent agg / h_s1
    float* aggd = ws + o; o += (size_t)ND * DH;                   // layer-1 doc agg / h_d1
    // layer-2 buffers reuse ys1/yd1 space (dead after combine1)
    float* ys2 = ys1;                                             // 100000 x 384
    float* yd2 = yd1;                                             // 10000 x 256
    float* aggs2 = ys1 + (size_t)NS * 384;                        // 100000 x 128
    float* aggd2 = aggs2 + (size_t)NS * 128;                      // 10000 x 128

    // ---- build concatenated weights ----
    long long t1 = (long long)DIN * DH;   // 196608
    long long t2 = (long long)DH * DOo;   // 32768
    int bt1 = (int)CDIV(t1, 256), bt2 = (int)CDIV(t2, 256);
    fill_basis_block<<<bt1, 256, 0, stream>>>(B1s, 3 * DH, 0,      basis1, t1, coeff1, 0, DH, t1);
    fill_basis_block<<<bt1, 256, 0, stream>>>(B1s, 3 * DH, DH,     basis1, t1, coeff1, 2, DH, t1);
    fill_copy_block <<<bt1, 256, 0, stream>>>(B1s, 3 * DH, 2 * DH, loopw1, DH, t1);
    fill_basis_block<<<bt1, 256, 0, stream>>>(B1d, 2 * DH, 0,      basis1, t1, coeff1, 1, DH, t1);
    fill_copy_block <<<bt1, 256, 0, stream>>>(B1d, 2 * DH, DH,     loopw1, DH, t1);
    fill_basis_block<<<bt2, 256, 0, stream>>>(B2s, 3 * DOo, 0,       basis2, t2, coeff2, 0, DOo, t2);
    fill_basis_block<<<bt2, 256, 0, stream>>>(B2s, 3 * DOo, DOo,     basis2, t2, coeff2, 2, DOo, t2);
    fill_copy_block <<<bt2, 256, 0, stream>>>(B2s, 3 * DOo, 2 * DOo, loopw2, DOo, t2);
    fill_basis_block<<<bt2, 256, 0, stream>>>(B2d, 2 * DOo, 0,   basis2, t2, coeff2, 1, DOo, t2);
    fill_copy_block <<<bt2, 256, 0, stream>>>(B2d, 2 * DOo, DOo, loopw2, DOo, t2);

    // ---- degrees (shared by both layers) ----
    long long ndeg = (long long)NS + NS + ND;
    zero_f4<<<(int)CDIV(ndeg / 4, 256), 256, 0, stream>>>((float4*)invdeg_ss, ndeg / 4);
    accum_deg<<<CDIV(E_SS, 256), 256, 0, stream>>>(dst_ss, E_SS, invdeg_ss);
    accum_deg<<<CDIV(E_DS, 256), 256, 0, stream>>>(dst_ds, E_DS, invdeg_ds);
    accum_deg<<<CDIV(E_SD, 256), 256, 0, stream>>>(dst_sd, E_SD, invdeg_sd);
    invert_deg<<<(int)CDIV(ndeg, 256), 256, 0, stream>>>(invdeg_ss, (int)ndeg);

    // ---- layer 1 GEMMs: ys1 = x_sent @ B1s ; yd1 = x_doc @ B1d ----
    {
        dim3 g(CDIV(NS, 64), (3 * DH) / 64);
        gemm_f32<<<g, 256, 0, stream>>>(x_sent, B1s, ys1, NS, DIN, 3 * DH);
    }
    {
        dim3 g(CDIV(ND, 64), (2 * DH) / 64);
        gemm_f32<<<g, 256, 0, stream>>>(x_doc, B1d, yd1, ND, DIN, 2 * DH);
    }

    // ---- layer 1 aggregation ----
    long long nagg1 = ((long long)NS + ND) * DH;
    zero_f4<<<(int)CDIV(nagg1 / 4, 256), 256, 0, stream>>>((float4*)aggs, nagg1 / 4);
    scatter_mean<<<(int)CDIV((long long)E_SD * 64, 256), 256, 0, stream>>>(
        ys1, 3 * DH, 0, src_sd, dst_sd, invdeg_sd, aggd, DH, 6, (long long)E_SD * 64);
    scatter_mean<<<(int)CDIV((long long)E_DS * 64, 256), 256, 0, stream>>>(
        yd1, 2 * DH, 0, src_ds, dst_ds, invdeg_ds, aggs, DH, 6, (long long)E_DS * 64);
    scatter_mean<<<(int)CDIV((long long)E_SS * 64, 256), 256, 0, stream>>>(
        ys1, 3 * DH, DH, src_ss, dst_ss, invdeg_ss, aggs, DH, 6, (long long)E_SS * 64);
    combine_relu<<<(int)CDIV((long long)NS * 64, 256), 256, 0, stream>>>(
        aggs, ys1, 3 * DH, 2 * DH, bias1, DH, 6, (long long)NS * 64);
    combine_relu<<<(int)CDIV((long long)ND * 64, 256), 256, 0, stream>>>(
        aggd, yd1, 2 * DH, DH, bias1, DH, 6, (long long)ND * 64);

    // ---- layer 2 GEMMs: ys2 = h_s1 @ B2s ; yd2 = h_d1 @ B2d ----
    {
        dim3 g(CDIV(NS, 64), (3 * DOo) / 64);
        gemm_f32<<<g, 256, 0, stream>>>(aggs, B2s, ys2, NS, DH, 3 * DOo);
    }
    {
        dim3 g(CDIV(ND, 64), (2 * DOo) / 64);
        gemm_f32<<<g, 256, 0, stream>>>(aggd, B2d, yd2, ND, DH, 2 * DOo);
    }

    // ---- layer 2 aggregation ----
    long long nagg2 = ((long long)NS + ND) * DOo;
    zero_f4<<<(int)CDIV(nagg2 / 4, 256), 256, 0, stream>>>((float4*)aggs2, nagg2 / 4);
    scatter_mean<<<(int)CDIV((long long)E_SD * 32, 256), 256, 0, stream>>>(
        ys2, 3 * DOo, 0, src_sd, dst_sd, invdeg_sd, aggd2, DOo, 5, (long long)E_SD * 32);
    scatter_mean<<<(int)CDIV((long long)E_DS * 32, 256), 256, 0, stream>>>(
        yd2, 2 * DOo, 0, src_ds, dst_ds, invdeg_ds, aggs2, DOo, 5, (long long)E_DS * 32);
    scatter_mean<<<(int)CDIV((long long)E_SS * 32, 256), 256, 0, stream>>>(
        ys2, 3 * DOo, DOo, src_ss, dst_ss, invdeg_ss, aggs2, DOo, 5, (long long)E_SS * 32);
    combine_relu<<<(int)CDIV((long long)NS * 32, 256), 256, 0, stream>>>(
        aggs2, ys2, 3 * DOo, 2 * DOo, bias2, DOo, 5, (long long)NS * 32);
    combine_relu<<<(int)CDIV((long long)ND * 32, 256), 256, 0, stream>>>(
        aggd2, yd2, 2 * DOo, DOo, bias2, DOo, 5, (long long)ND * 32);

    // ---- readout ----
    init_out<<<1, 64, 0, stream>>>(out, bscore, G);
    score_reduce<<<512, 256, 0, stream>>>(aggs2, wscore, gid_sent, DOo, NS, out, G);
    score_reduce<<<128, 256, 0, stream>>>(aggd2, wscore, gid_doc, DOo, ND, out, G);
}